// Round 9
// baseline (73.931 us; speedup 1.0000x reference)
//
#include <hip/hip_runtime.h>
#include <hip/hip_bf16.h>

// kernel[i,j] = | prod_k cos((x[i,k]-y[j,k])/2) |
//             = | prod_k ( cos(x/2)cos(y/2) + sin(x/2)sin(y/2) ) |
// Inputs float32, output float32 (established r0-r3).
//
// History: r4 66.3 | r5 168 (VGPR-cap spills, launch_bounds(256,4) footgun)
//          r7 65.25 (NT stores) | r8 64.26 (64x64, 4 blk/CU)
// Envelope calibration (r5): dur - qkern_dispatch ~= 50 us of harness fills/
// overhead => r8's qkern ~ 15 us vs ~5 us floors; LDS per-lane reads (4 b128
// per output) are the modeled hot spot.
//
// r9 rewrite: two kernels, no LDS in the hot loop.
//   precs: sincos once per input element into d_ws:
//          csx[row][k]=(c,s) row-contiguous 128 B (s_load-able),
//          csy_t[k][col]=(c,s) transposed (coalesced lane loads).
//   qkern: 64-thread blocks (single wave) => row addresses provably uniform
//          => s_load row factors (SGPR broadcast). Lane holds 2 cols' factors
//          for all 16 k in 64 VGPRs. Per row: ~96 VALU + 1 NT float2 store.
//          Zero LDS, zero barriers.

constexpr int D  = 16;     // wires
constexpr int RPB = 16;    // rows per (single-wave) block
constexpr int CPW = 128;   // cols per wave (2 per lane)

typedef float vf2 __attribute__((ext_vector_type(2)));

__global__ __launch_bounds__(256)
void precs(const float* __restrict__ x, const float* __restrict__ y,
           float2* __restrict__ csx, float2* __restrict__ csy_t,
           int nx, int m) {
    const int gid = blockIdx.x * 256 + threadIdx.x;
    if (gid < nx) {
        // csx[row*16+k]: contiguous read of x, contiguous float2 write.
        float s, c;
        __sincosf(0.5f * x[gid], &s, &c);
        csx[gid] = make_float2(c, s);
    } else {
        // j = k*m + col  (contiguous float2 write of csy_t)
        const int j = gid - nx;
        const int k = j / m, col = j - k * m;
        float s, c;
        __sincosf(0.5f * y[(size_t)col * D + k], &s, &c);
        csy_t[j] = make_float2(c, s);
    }
}

__global__ __launch_bounds__(64)
void qkern(const float2* __restrict__ csx, const float2* __restrict__ csy_t,
           float* __restrict__ out, int m) {
    const int lane = threadIdx.x;
    const int col0 = blockIdx.x * CPW + lane * 2;   // 2 cols per lane
    const int rbase = blockIdx.y * RPB;

    // Column factors for all 16 wires: (c0,s0,c1,s1) per k. 64 VGPRs.
    float4 colf[D];
#pragma unroll
    for (int k = 0; k < D; ++k)
        colf[k] = *(const float4*)(csy_t + (size_t)k * m + col0);

    // Row factors: wave-uniform address -> scalar loads.
    const float2* rp = csx + (size_t)rbase * D;

#pragma unroll 4
    for (int i = 0; i < RPB; ++i) {
        float p0 = 1.0f, p1 = 1.0f;
#pragma unroll
        for (int k = 0; k < D; ++k) {
            const float cxk = rp[i * D + k].x;
            const float sxk = rp[i * D + k].y;
            const float t0 = cxk * colf[k].x + sxk * colf[k].y;
            const float t1 = cxk * colf[k].z + sxk * colf[k].w;
            p0 *= t0;
            p1 *= t1;
        }
        vf2 v;
        v.x = fabsf(p0);
        v.y = fabsf(p1);
        __builtin_nontemporal_store(
            v, (vf2*)(out + (size_t)(rbase + i) * m + col0));
    }
}

extern "C" void kernel_launch(void* const* d_in, const int* in_sizes, int n_in,
                              void* d_out, int out_size, void* d_ws, size_t ws_size,
                              hipStream_t stream) {
    const float* x = (const float*)d_in[0];
    const float* y = (const float*)d_in[1];
    float* out = (float*)d_out;
    const int n = in_sizes[0] / D;   // 2048
    const int m = in_sizes[1] / D;   // 2048

    float2* csx   = (float2*)d_ws;                      // n*16 float2 (256 KB)
    float2* csy_t = (float2*)d_ws + (size_t)n * D;      // m*16 float2 (256 KB)

    const int nx = n * D, ny = m * D;
    precs<<<(nx + ny + 255) / 256, 256, 0, stream>>>(x, y, csx, csy_t, nx, m);

    dim3 grid(m / CPW, n / RPB);     // 16 x 128 = 2048 single-wave blocks
    qkern<<<grid, 64, 0, stream>>>(csx, csy_t, out, m);
}

// Round 10
// 68.778 us; speedup vs baseline: 1.0749x; 1.0749x over previous
//
#include <hip/hip_runtime.h>
#include <hip/hip_bf16.h>

// kernel[i,j] = | prod_{k<16} cos((x[i,k]-y[j,k])/2) |
// Inputs f32, output f32 (established r0-r3).
//
// MFMA formulation (r10): for each PAIR p of wires,
//   cos(a)cos(b) = 1/2[cos(Rm-Cm) + cos(Rp-Cp)],  Rm=(x0-x1)/2, Rp=(x0+x1)/2
// which is a 4-term separable dot (row factors {cRm,sRm,cRp,sRp}/2,
// col factors {cCm,sCm,cCp,sCp}). A QUAD (pair x pair) is then a 16-term
// separable dot:  Q_q[i,j] = sum_t A_q[i,t] * B_q[j,t],  t<16,
// and out = |Q0*Q1*Q2*Q3|. Each quad = one mfma_f32_16x16x32_bf16 with
// K-slots 16..31 zeroed (lanes with lane>>4 >= 2 hold 0).
// Precision: one bf16 rounding per A/B term; sum|A||B| <= 1 per quad
// -> expected absmax ~5e-3 << 1.56e-2 threshold.
//
// precs: expands each row of x / col of y into 64 bf16 terms (4 quads x 16).
// qkern: 64x64 out-tile per 256-thread block (4 waves x 16 rows); frag loads
//        straight from L2-resident ws (512 KB); no LDS, no barriers.

constexpr int D = 16;

typedef short  bf16x8 __attribute__((ext_vector_type(8)));
typedef float  f32x4  __attribute__((ext_vector_type(4)));

static __device__ inline unsigned int pk2(float a, float b) {
    __hip_bfloat16 ha = __float2bfloat16(a);
    __hip_bfloat16 hb = __float2bfloat16(b);
    unsigned short ua, ub;
    __builtin_memcpy(&ua, &ha, 2);
    __builtin_memcpy(&ub, &hb, 2);
    return (unsigned int)ua | ((unsigned int)ub << 16);
}

// One thread per row (u<n: row u of Arow from x) or col (u-n of Bcol from y).
__global__ __launch_bounds__(256)
void precs(const float* __restrict__ x, const float* __restrict__ y,
           unsigned short* __restrict__ Arow, unsigned short* __restrict__ Bcol,
           int n, int ntot) {
    const int u = blockIdx.x * 256 + threadIdx.x;
    if (u >= ntot) return;
    const bool isrow = (u < n);
    const float* src = isrow ? (x + (size_t)u * D) : (y + (size_t)(u - n) * D);
    unsigned short* dst =
        isrow ? (Arow + (size_t)u * 64) : (Bcol + (size_t)(u - n) * 64);
    const float scale = isrow ? 0.5f : 1.0f;   // 1/2 per pair, rows only

    float f[8][4];
#pragma unroll
    for (int p = 0; p < 8; ++p) {
        const float a0 = src[2 * p], a1 = src[2 * p + 1];
        float sm, cm, sp, cp;
        __sincosf(0.5f * (a0 - a1), &sm, &cm);
        __sincosf(0.5f * (a0 + a1), &sp, &cp);
        f[p][0] = scale * cm; f[p][1] = scale * sm;
        f[p][2] = scale * cp; f[p][3] = scale * sp;
    }
#pragma unroll
    for (int q = 0; q < 4; ++q) {
        // term[t = uu*4+v] = f[2q][uu] * f[2q+1][v]  (k-slot order, same for A/B)
        uint4 lo, hi;
        lo.x = pk2(f[2*q][0]*f[2*q+1][0], f[2*q][0]*f[2*q+1][1]);
        lo.y = pk2(f[2*q][0]*f[2*q+1][2], f[2*q][0]*f[2*q+1][3]);
        lo.z = pk2(f[2*q][1]*f[2*q+1][0], f[2*q][1]*f[2*q+1][1]);
        lo.w = pk2(f[2*q][1]*f[2*q+1][2], f[2*q][1]*f[2*q+1][3]);
        hi.x = pk2(f[2*q][2]*f[2*q+1][0], f[2*q][2]*f[2*q+1][1]);
        hi.y = pk2(f[2*q][2]*f[2*q+1][2], f[2*q][2]*f[2*q+1][3]);
        hi.z = pk2(f[2*q][3]*f[2*q+1][0], f[2*q][3]*f[2*q+1][1]);
        hi.w = pk2(f[2*q][3]*f[2*q+1][2], f[2*q][3]*f[2*q+1][3]);
        *(uint4*)(dst + q * 16)     = lo;
        *(uint4*)(dst + q * 16 + 8) = hi;
    }
}

__global__ __launch_bounds__(256)
void qkern(const unsigned short* __restrict__ Arow,
           const unsigned short* __restrict__ Bcol,
           float* __restrict__ out, int m) {
    const int tid  = threadIdx.x;
    const int wave = tid >> 6;
    const int lane = tid & 63;
    const int m16  = lane & 15;
    const int half = lane >> 4;          // k-block; halves 2,3 carry zeros
    const int row0 = blockIdx.x * 64 + wave * 16;
    const int col0 = blockIdx.y * 64;

    const bf16x8 zf = {0, 0, 0, 0, 0, 0, 0, 0};
    const f32x4  zc = {0.f, 0.f, 0.f, 0.f};

    // A-frags: A[mrow = lane&15][k = (lane>>4)*8 + j]  (verified layout, m89)
    bf16x8 af[4];
#pragma unroll
    for (int q = 0; q < 4; ++q)
        af[q] = (half < 2)
            ? *(const bf16x8*)(Arow + (size_t)(row0 + m16) * 64 + q * 16 + half * 8)
            : zf;

#pragma unroll
    for (int cg = 0; cg < 4; ++cg) {
        const int colb = col0 + cg * 16;
        f32x4 acc[4];
#pragma unroll
        for (int q = 0; q < 4; ++q) {
            const bf16x8 bfq = (half < 2)
                ? *(const bf16x8*)(Bcol + (size_t)(colb + m16) * 64 + q * 16 + half * 8)
                : zf;
            acc[q] = __builtin_amdgcn_mfma_f32_16x16x32_bf16(af[q], bfq, zc, 0, 0, 0);
        }
        // C/D: col = lane&15, row = (lane>>4)*4 + reg  (verified m89/m91)
#pragma unroll
        for (int r = 0; r < 4; ++r) {
            const float v =
                fabsf(acc[0][r] * acc[1][r] * acc[2][r] * acc[3][r]);
            const int row = row0 + half * 4 + r;
            __builtin_nontemporal_store(v, out + (size_t)row * m + colb + m16);
        }
    }
}

extern "C" void kernel_launch(void* const* d_in, const int* in_sizes, int n_in,
                              void* d_out, int out_size, void* d_ws, size_t ws_size,
                              hipStream_t stream) {
    const float* x = (const float*)d_in[0];
    const float* y = (const float*)d_in[1];
    float* out = (float*)d_out;
    const int n = in_sizes[0] / D;   // 2048
    const int m = in_sizes[1] / D;   // 2048

    unsigned short* Arow = (unsigned short*)d_ws;          // n*64 bf16 (256 KB)
    unsigned short* Bcol = Arow + (size_t)n * 64;          // m*64 bf16 (256 KB)

    const int ntot = n + m;
    precs<<<(ntot + 255) / 256, 256, 0, stream>>>(x, y, Arow, Bcol, n, ntot);

    dim3 grid(n / 64, m / 64);       // 32 x 32 = 1024 blocks -> 4 blk/CU
    qkern<<<grid, 256, 0, stream>>>(Arow, Bcol, out, m);
}

// Round 11
// 62.219 us; speedup vs baseline: 1.1882x; 1.1054x over previous
//
#include <hip/hip_runtime.h>
#include <hip/hip_bf16.h>

// kernel[i,j] = | prod_{k<16} cos((x[i,k]-y[j,k])/2) |   (f32 in, f32 out)
//
// MFMA formulation (verified r10, absmax 0.0039): per wire-pair
//   cos(a)cos(b) = 1/2[cos(Rm-Cm) + cos(Rp-Cp)]  -> 4-term separable dot;
// a quad (pair x pair) is a 16-term dot  Q_q = sum_t A_q[i,t] B_q[j,t];
// out = |Q0 Q1 Q2 Q3|. One mfma_f32_16x16x32_bf16 per quad (K 16..31 = 0).
//
// r11 = r10 fused into ONE dispatch (r10's two-kernel split cost ~dispatch
// gap + latency-bound 16-block precs + L2-exposed frag loads):
//  - stage A/B term vectors in LDS per block (256 thr = 2/unit x 128 units,
//    8 sincos each), rows padded to 72 shorts (144 B): frag b128 reads are
//    2-way bank-aliased (free); 128 B rows would be 16-way.
//  - then r10's exact MFMA + scalar-NT-store code, frags from LDS.
// Per-CU model: staging ~1 us, 20 ds_read_b128/wave = 1.6 us, MFMA 0.5 us,
// stores 16.8 MB NT ~2.7 us (overlapped) -> kernel ~5-6 us.

constexpr int D = 16;
constexpr int RSTR = 72;   // LDS row stride in shorts (144 B)

typedef short  bf16x8 __attribute__((ext_vector_type(8)));
typedef float  f32x4  __attribute__((ext_vector_type(4)));

static __device__ inline unsigned int pk2(float a, float b) {
    __hip_bfloat16 ha = __float2bfloat16(a);
    __hip_bfloat16 hb = __float2bfloat16(b);
    unsigned short ua, ub;
    __builtin_memcpy(&ua, &ha, 2);
    __builtin_memcpy(&ub, &hb, 2);
    return (unsigned int)ua | ((unsigned int)ub << 16);
}

__global__ __launch_bounds__(256)
void qkern(const float* __restrict__ x, const float* __restrict__ y,
           float* __restrict__ out, int m) {
    __shared__ unsigned short Al[64 * RSTR];   // A terms: 64 rows x 64 bf16
    __shared__ unsigned short Bl[64 * RSTR];   // B terms: 64 cols x 64 bf16

    const int tid  = threadIdx.x;
    const int row0b = blockIdx.x * 64;
    const int col0b = blockIdx.y * 64;

    // ---- Stage: 128 units (64 rows, 64 cols), 2 threads/unit. ----
    {
        const int u    = tid >> 1;          // unit 0..127
        const int half = tid & 1;           // pairs 4h..4h+3, quads 2h,2h+1
        const bool isrow = (u < 64);
        const float* src = isrow ? (x + (size_t)(row0b + u) * D)
                                 : (y + (size_t)(col0b + (u - 64)) * D);
        unsigned short* dst = (isrow ? Al + (size_t)u * RSTR
                                     : Bl + (size_t)(u - 64) * RSTR);
        const float scale = isrow ? 0.5f : 1.0f;   // 1/2 per pair, rows only

        float f[4][4];                      // this thread's 4 pairs
#pragma unroll
        for (int pp = 0; pp < 4; ++pp) {
            const int p = half * 4 + pp;
            const float a0 = src[2 * p], a1 = src[2 * p + 1];
            float sm, cm, sp, cp;
            __sincosf(0.5f * (a0 - a1), &sm, &cm);
            __sincosf(0.5f * (a0 + a1), &sp, &cp);
            f[pp][0] = scale * cm; f[pp][1] = scale * sm;
            f[pp][2] = scale * cp; f[pp][3] = scale * sp;
        }
#pragma unroll
        for (int qq = 0; qq < 2; ++qq) {    // quads 2*half+qq use pairs 2qq,2qq+1
            const int q = half * 2 + qq;
            const float* fa = f[2 * qq];
            const float* fb = f[2 * qq + 1];
            uint4 lo, hi;
            lo.x = pk2(fa[0] * fb[0], fa[0] * fb[1]);
            lo.y = pk2(fa[0] * fb[2], fa[0] * fb[3]);
            lo.z = pk2(fa[1] * fb[0], fa[1] * fb[1]);
            lo.w = pk2(fa[1] * fb[2], fa[1] * fb[3]);
            hi.x = pk2(fa[2] * fb[0], fa[2] * fb[1]);
            hi.y = pk2(fa[2] * fb[2], fa[2] * fb[3]);
            hi.z = pk2(fa[3] * fb[0], fa[3] * fb[1]);
            hi.w = pk2(fa[3] * fb[2], fa[3] * fb[3]);
            *(uint4*)(dst + q * 16)     = lo;
            *(uint4*)(dst + q * 16 + 8) = hi;
        }
    }
    __syncthreads();

    // ---- MFMA phase (identical structure to verified r10). ----
    const int wave = tid >> 6;
    const int lane = tid & 63;
    const int m16  = lane & 15;
    const int kh   = lane >> 4;          // k-block; 2,3 carry zeros
    const int rw0  = wave * 16;          // wave's 16-row band within tile

    const bf16x8 zf = {0, 0, 0, 0, 0, 0, 0, 0};
    const f32x4  zc = {0.f, 0.f, 0.f, 0.f};

    bf16x8 af[4];
#pragma unroll
    for (int q = 0; q < 4; ++q)
        af[q] = (kh < 2)
            ? *(const bf16x8*)(Al + (size_t)(rw0 + m16) * RSTR + q * 16 + kh * 8)
            : zf;

#pragma unroll
    for (int cg = 0; cg < 4; ++cg) {
        f32x4 acc[4];
#pragma unroll
        for (int q = 0; q < 4; ++q) {
            const bf16x8 bfq = (kh < 2)
                ? *(const bf16x8*)(Bl + (size_t)(cg * 16 + m16) * RSTR + q * 16 + kh * 8)
                : zf;
            acc[q] = __builtin_amdgcn_mfma_f32_16x16x32_bf16(af[q], bfq, zc, 0, 0, 0);
        }
        // C/D: col = lane&15, row = (lane>>4)*4 + reg  (verified m89/r10)
#pragma unroll
        for (int r = 0; r < 4; ++r) {
            const float v = fabsf(acc[0][r] * acc[1][r] * acc[2][r] * acc[3][r]);
            const int row = row0b + rw0 + kh * 4 + r;
            __builtin_nontemporal_store(v, out + (size_t)row * m + col0b + cg * 16 + m16);
        }
    }
}

extern "C" void kernel_launch(void* const* d_in, const int* in_sizes, int n_in,
                              void* d_out, int out_size, void* d_ws, size_t ws_size,
                              hipStream_t stream) {
    const float* x = (const float*)d_in[0];
    const float* y = (const float*)d_in[1];
    float* out = (float*)d_out;
    const int n = in_sizes[0] / D;   // 2048
    const int m = in_sizes[1] / D;   // 2048

    dim3 grid(n / 64, m / 64);       // 32 x 32 = 1024 blocks -> 4 blk/CU
    qkern<<<grid, 256, 0, stream>>>(x, y, out, m);
}